// Round 1
// baseline (139.951 us; speedup 1.0000x reference)
//
#include <hip/hip_runtime.h>
#include <math.h>

// QuanvolutionPlus: conv(s2,p1)+BN+ReLU branch  +  2-qubit quantum patch branch,
// fused add, 784->10 linear, log_softmax.  B=16384, fp32 in/out.
//
// Layout facts (verified against reference):
//   cls flat idx  n = c*196 + (i*14+j)         (h.reshape(b,-1) of [B,4,14,14])
//   q   flat idx  n = (i*14+j)*4 + k           ([B,14,14,4].reshape(b,-1))
//   logits[o] = sum_n (cls[n]+q[n]) * lin_w[o*784+n] + lin_b[o]
//
// One wave per sample; quantum float4 for patch p stays in the registers of the
// lane that consumes fused chunk p in the matvec (chunk p = lane p%64, iter p/64).

#define NW 4                 // waves per block
#define IMG_STRIDE 36        // padded row stride (floats); %4==0 for float4 stores
#define IMG_F4 264           // ceil(29*36/16B) -> 1056 floats = 264 float4

__global__ __launch_bounds__(256, 2)
void quanv_fused(const float* __restrict__ x,
                 const float* __restrict__ conv_w,
                 const float* __restrict__ bn_gamma,
                 const float* __restrict__ bn_beta,
                 const float* __restrict__ bn_mean,
                 const float* __restrict__ bn_var,
                 const float* __restrict__ var_params,
                 const float* __restrict__ lin_w,
                 const float* __restrict__ lin_b,
                 float* __restrict__ out, int B)
{
    __shared__ __align__(16) float sW[7840];               // 31360 B
    __shared__ __align__(16) float simg[NW][IMG_F4 * 4];   // 16896 B
    __shared__ __align__(16) float scls[NW][784];          // 12544 B

    const int tid  = threadIdx.x;
    const int wave = tid >> 6;
    const int lane = tid & 63;
    const int sample = blockIdx.x * NW + wave;
    const bool active = (sample < B);

    // ---- zero the padded image tile (per wave) ----
    {
        float4* z = (float4*)simg[wave];
        #pragma unroll
        for (int t = 0; t < 5; ++t) {
            int idx = lane + t * 64;
            if (idx < IMG_F4) z[idx] = make_float4(0.f, 0.f, 0.f, 0.f);
        }
    }

    // ---- cooperative stage of lin_w into LDS (whole block) ----
    {
        const float4* src = (const float4*)lin_w;
        float4* dst = (float4*)sW;
        #pragma unroll
        for (int t = 0; t < 8; ++t) {
            int i = tid + t * 256;
            if (i < 1960) dst[i] = src[i];
        }
    }

    __syncthreads();  // zero-fill complete before pixel writes land

    // ---- load this wave's image into the padded tile ----
    // pixel (r,c) lives at (r+1)*IMG_STRIDE + 4 + c ; rows are 7 float4 each (28%4==0)
    if (active) {
        const float4* xs = (const float4*)(x + (size_t)sample * 784);
        #pragma unroll
        for (int t = 0; t < 4; ++t) {
            int g = lane + t * 64;
            if (g < 196) {
                float4 v = xs[g];
                int row  = (unsigned)g / 7u;
                int colb = (g - row * 7) * 4;
                *(float4*)&simg[wave][(row + 1) * IMG_STRIDE + 4 + colb] = v;
            }
        }
    }

    // ---- uniform small params (scalar loads) ----
    float w[36];
    #pragma unroll
    for (int k = 0; k < 36; ++k) w[k] = conv_w[k];
    float inv[4], addc[4];
    #pragma unroll
    for (int c = 0; c < 4; ++c) {
        float iv = bn_gamma[c] * rsqrtf(bn_var[c] + 1e-5f);
        inv[c]  = iv;
        addc[c] = bn_beta[c] - bn_mean[c] * iv;
    }
    float cv[4], sv[4];
    #pragma unroll
    for (int k = 0; k < 4; ++k) __sincosf(var_params[k] * 0.5f, &sv[k], &cv[k]);

    __syncthreads();  // image pixels + W visible to all lanes

    // ---- per-patch: conv(4ch)+BN+ReLU -> LDS ; quantum 4-vec -> registers ----
    float4 qf[4];
    #pragma unroll
    for (int t = 0; t < 4; ++t) qf[t] = make_float4(0.f, 0.f, 0.f, 0.f);

    if (active) {
        const float* im = simg[wave];
        #pragma unroll
        for (int t = 0; t < 4; ++t) {
            int p = lane + t * 64;
            if (p < 196) {
                int i = (unsigned)p / 14u;
                int j = p - i * 14;
                int base = (2 * i) * IMG_STRIDE + 3 + 2 * j;   // img row 2i-1, col 2j-1
                float a00 = im[base + 0],               a01 = im[base + 1],               a02 = im[base + 2];
                float a10 = im[base + IMG_STRIDE + 0],  a11 = im[base + IMG_STRIDE + 1],  a12 = im[base + IMG_STRIDE + 2];
                float a20 = im[base + 2*IMG_STRIDE + 0],a21 = im[base + 2*IMG_STRIDE + 1],a22 = im[base + 2*IMG_STRIDE + 2];

                #pragma unroll
                for (int c = 0; c < 4; ++c) {
                    float h = w[c*9+0]*a00 + w[c*9+1]*a01 + w[c*9+2]*a02
                            + w[c*9+3]*a10 + w[c*9+4]*a11 + w[c*9+5]*a12
                            + w[c*9+6]*a20 + w[c*9+7]*a21 + w[c*9+8]*a22;
                    h = h * inv[c] + addc[c];
                    scls[wave][c * 196 + p] = fmaxf(h, 0.f);
                }

                // quantum patch pixels: x[2i][2j]=a11, x[2i][2j+1]=a12, x[2i+1][2j]=a21, x[2i+1][2j+1]=a22
                float ha = 0.5f * (a11 + a21);
                float hb = 0.5f * (a12 + a22);
                float c0, s0, c1, s1;
                __sincosf(ha, &s0, &c0);
                __sincosf(hb, &s1, &c1);
                // state after encoding + CNOT(0->1) (row1 reversed)
                float m00 = c0*c1, m01 = c0*s1;
                float m10 = s0*s1, m11 = s0*c1;
                // RY(v0) on wire0
                float t00 = cv[0]*m00 - sv[0]*m10, t01 = cv[0]*m01 - sv[0]*m11;
                float t10 = sv[0]*m00 + cv[0]*m10, t11 = sv[0]*m01 + cv[0]*m11;
                // RY(v1) on wire1
                float u00 = cv[1]*t00 - sv[1]*t01, u01 = sv[1]*t00 + cv[1]*t01;
                float u10 = cv[1]*t10 - sv[1]*t11, u11 = sv[1]*t10 + cv[1]*t11;
                // CNOT(1->0): column1 rows swap
                float tmp = u01; u01 = u11; u11 = tmp;
                // RY(v2) on wire0
                float p00 = cv[2]*u00 - sv[2]*u10, p01 = cv[2]*u01 - sv[2]*u11;
                float p10 = sv[2]*u00 + cv[2]*u10, p11 = sv[2]*u01 + cv[2]*u11;
                // RY(v3) on wire1
                float q00 = cv[3]*p00 - sv[3]*p01, q01 = sv[3]*p00 + cv[3]*p01;
                float q10 = cv[3]*p10 - sv[3]*p11, q11 = sv[3]*p10 + cv[3]*p11;

                float z0 = q00*q00 + q01*q01 - q10*q10 - q11*q11;
                float z1 = q00*q00 + q10*q10 - q01*q01 - q11*q11;
                float x0 = 2.f * (q00*q10 + q01*q11);
                float x1 = 2.f * (q00*q01 + q10*q11);
                qf[t] = make_float4(z0, z1, x0, x1);
            }
        }
    }

    __syncthreads();  // scls writes visible cross-lane

    // ---- fused matvec: logits[o] = sum over this lane's float4 chunks, wave-reduced ----
    float lg[10];
    if (active) {
        float4 f[4];
        #pragma unroll
        for (int t = 0; t < 4; ++t) {
            int p = lane + t * 64;
            if (p < 196) {
                float4 cl = *(const float4*)&scls[wave][4 * p];
                f[t] = make_float4(cl.x + qf[t].x, cl.y + qf[t].y,
                                   cl.z + qf[t].z, cl.w + qf[t].w);
            } else {
                f[t] = make_float4(0.f, 0.f, 0.f, 0.f);
            }
        }
        #pragma unroll
        for (int o = 0; o < 10; ++o) {
            const float4* wr = (const float4*)&sW[o * 784];
            float s = 0.f;
            #pragma unroll
            for (int t = 0; t < 4; ++t) {
                int p = lane + t * 64;
                if (p < 196) {
                    float4 wv = wr[p];
                    s += f[t].x * wv.x + f[t].y * wv.y + f[t].z * wv.z + f[t].w * wv.w;
                }
            }
            #pragma unroll
            for (int m = 1; m < 64; m <<= 1) s += __shfl_xor(s, m, 64);
            lg[o] = s + lin_b[o];
        }

        // log_softmax over 10 (all lanes hold identical lg[])
        float mx = lg[0];
        #pragma unroll
        for (int o = 1; o < 10; ++o) mx = fmaxf(mx, lg[o]);
        float se = 0.f;
        #pragma unroll
        for (int o = 0; o < 10; ++o) se += __expf(lg[o] - mx);
        float ls = __logf(se);

        if (lane < 10) {
            float v = lg[0];
            #pragma unroll
            for (int o = 1; o < 10; ++o) if (lane == o) v = lg[o];
            out[(size_t)sample * 10 + lane] = v - mx - ls;
        }
    }
}

extern "C" void kernel_launch(void* const* d_in, const int* in_sizes, int n_in,
                              void* d_out, int out_size, void* d_ws, size_t ws_size,
                              hipStream_t stream) {
    const float* x          = (const float*)d_in[0];
    const float* conv_w     = (const float*)d_in[1];
    const float* bn_gamma   = (const float*)d_in[2];
    const float* bn_beta    = (const float*)d_in[3];
    const float* bn_mean    = (const float*)d_in[4];
    const float* bn_var     = (const float*)d_in[5];
    const float* var_params = (const float*)d_in[6];
    const float* lin_w      = (const float*)d_in[7];
    const float* lin_b      = (const float*)d_in[8];
    float* out = (float*)d_out;

    const int B = in_sizes[0] / 784;
    const int blocks = (B + NW - 1) / NW;
    quanv_fused<<<blocks, 256, 0, stream>>>(x, conv_w, bn_gamma, bn_beta, bn_mean,
                                            bn_var, var_params, lin_w, lin_b, out, B);
}

// Round 2
// 119.602 us; speedup vs baseline: 1.1701x; 1.1701x over previous
//
#include <hip/hip_runtime.h>
#include <math.h>

// QuanvolutionPlus fused kernel, round 2.
// Changes vs round 1 (which was LDS-pipe + occupancy bound at 74us steady):
//  - lin_w no longer staged to LDS: read from global (L2-resident, coalesced).
//    LDS/block 60928 -> ~29.2KB -> 5 blocks/CU (was 2).
//  - shuffle reduce (60 ds_swizzle/sample) replaced by DPP v_add_f32 reduce (VALU pipe).
//  - no __syncthreads at all: simg/scls are per-wave; wave-local lgkmcnt fences only.
//  - halo-only zeroing of the image tile (2 scalar writes, no pre-barrier).
//
// Layout facts (verified):
//   cls flat idx n = c*196 + (i*14+j);  q flat idx n = (i*14+j)*4 + k
//   logits[o] = sum_n (cls[n]+q[n]) * lin_w[o*784+n] + lin_b[o]

#define NW 4                  // waves per block
#define IMG_STRIDE 36         // padded row stride (floats), %4==0 for float4 stores
#define IMG_WORDS (29 * 36)   // rows -1..27, cols -1..30 (pixel col c at offset 4+c)

__device__ __forceinline__ void lds_fence() {
    // per-wave ordering of LDS write->read (cross-lane, same wave). No cross-wave
    // sharing exists in this kernel, so no s_barrier is needed.
    asm volatile("s_waitcnt lgkmcnt(0)" ::: "memory");
}

__device__ __forceinline__ float wave64_sum(float x) {
    // gfx9 DPP reduction: row prefix (shr 1,2,4,8) then row_bcast15/31.
    // Full sum lands in lane 63; broadcast via readlane. All VALU, no DS pipe.
    int v;
    v = __builtin_amdgcn_update_dpp(0, __float_as_int(x), 0x111, 0xf, 0xf, true); x += __int_as_float(v);
    v = __builtin_amdgcn_update_dpp(0, __float_as_int(x), 0x112, 0xf, 0xf, true); x += __int_as_float(v);
    v = __builtin_amdgcn_update_dpp(0, __float_as_int(x), 0x114, 0xf, 0xf, true); x += __int_as_float(v);
    v = __builtin_amdgcn_update_dpp(0, __float_as_int(x), 0x118, 0xf, 0xf, true); x += __int_as_float(v);
    v = __builtin_amdgcn_update_dpp(0, __float_as_int(x), 0x142, 0xa, 0xf, true); x += __int_as_float(v);
    v = __builtin_amdgcn_update_dpp(0, __float_as_int(x), 0x143, 0xc, 0xf, true); x += __int_as_float(v);
    return __int_as_float(__builtin_amdgcn_readlane(__float_as_int(x), 63));
}

__global__ __launch_bounds__(256, 4)
void quanv_fused(const float* __restrict__ x,
                 const float* __restrict__ conv_w,
                 const float* __restrict__ bn_gamma,
                 const float* __restrict__ bn_beta,
                 const float* __restrict__ bn_mean,
                 const float* __restrict__ bn_var,
                 const float* __restrict__ var_params,
                 const float* __restrict__ lin_w,
                 const float* __restrict__ lin_b,
                 float* __restrict__ out, int B)
{
    __shared__ __align__(16) float simg[NW][IMG_WORDS];  // 4*4176 B
    __shared__ __align__(16) float scls[NW][784];        // 4*3136 B

    const int tid  = threadIdx.x;
    const int wave = tid >> 6;
    const int lane = tid & 63;
    const int sample = blockIdx.x * NW + wave;
    const bool active = (sample < B);

    float* im = simg[wave];

    // ---- halo zeroing: img row -1 (tile row 0) and img col -1 (offset 3) ----
    // conv reads tile rows 0..28, col offsets 3..31; pixels cover rows 1..28,
    // offsets 4..31; only row 0 and offset-3 column need zeros.
    if (lane < 36) im[lane] = 0.f;
    if (lane < 28) im[(lane + 1) * IMG_STRIDE + 3] = 0.f;

    // ---- stage this wave's image (coalesced float4 global loads) ----
    if (active) {
        const float4* xs = (const float4*)(x + (size_t)sample * 784);
        #pragma unroll
        for (int t = 0; t < 4; ++t) {
            int g = lane + t * 64;
            if (g < 196) {
                float4 v = xs[g];
                int row  = (unsigned)g / 7u;
                int colb = (g - row * 7) * 4;
                *(float4*)&im[(row + 1) * IMG_STRIDE + 4 + colb] = v;
            }
        }
    }

    // ---- uniform small params (scalar loads, overlap with staging) ----
    float w[36];
    #pragma unroll
    for (int k = 0; k < 36; ++k) w[k] = conv_w[k];
    float inv[4], addc[4];
    #pragma unroll
    for (int c = 0; c < 4; ++c) {
        float iv = bn_gamma[c] * rsqrtf(bn_var[c] + 1e-5f);
        inv[c]  = iv;
        addc[c] = bn_beta[c] - bn_mean[c] * iv;
    }
    float cv[4], sv[4];
    #pragma unroll
    for (int k = 0; k < 4; ++k) __sincosf(var_params[k] * 0.5f, &sv[k], &cv[k]);

    lds_fence();  // img writes visible to all lanes of this wave

    // ---- per-patch conv(4ch)+BN+ReLU -> scls ; quantum float4 -> registers ----
    float4 qf[4];
    #pragma unroll
    for (int t = 0; t < 4; ++t) qf[t] = make_float4(0.f, 0.f, 0.f, 0.f);

    if (active) {
        #pragma unroll
        for (int t = 0; t < 4; ++t) {
            int p = lane + t * 64;
            if (p < 196) {
                int i = (unsigned)p / 14u;
                int j = p - i * 14;
                int base = (2 * i) * IMG_STRIDE + 3 + 2 * j;   // img (2i-1, 2j-1)
                float a00 = im[base + 0],                a01 = im[base + 1],                a02 = im[base + 2];
                float a10 = im[base + IMG_STRIDE + 0],   a11 = im[base + IMG_STRIDE + 1],   a12 = im[base + IMG_STRIDE + 2];
                float a20 = im[base + 2*IMG_STRIDE + 0], a21 = im[base + 2*IMG_STRIDE + 1], a22 = im[base + 2*IMG_STRIDE + 2];

                #pragma unroll
                for (int c = 0; c < 4; ++c) {
                    float h = w[c*9+0]*a00 + w[c*9+1]*a01 + w[c*9+2]*a02
                            + w[c*9+3]*a10 + w[c*9+4]*a11 + w[c*9+5]*a12
                            + w[c*9+6]*a20 + w[c*9+7]*a21 + w[c*9+8]*a22;
                    h = h * inv[c] + addc[c];
                    scls[wave][c * 196 + p] = fmaxf(h, 0.f);
                }

                // quantum patch: x[2i][2j]=a11, x[2i][2j+1]=a12, x[2i+1][2j]=a21, x[2i+1][2j+1]=a22
                float ha = 0.5f * (a11 + a21);
                float hb = 0.5f * (a12 + a22);
                float c0, s0, c1, s1;
                __sincosf(ha, &s0, &c0);
                __sincosf(hb, &s1, &c1);
                float m00 = c0*c1, m01 = c0*s1;
                float m10 = s0*s1, m11 = s0*c1;           // encoding + CNOT(0->1)
                float t00 = cv[0]*m00 - sv[0]*m10, t01 = cv[0]*m01 - sv[0]*m11;
                float t10 = sv[0]*m00 + cv[0]*m10, t11 = sv[0]*m01 + cv[0]*m11;  // RY(v0) w0
                float u00 = cv[1]*t00 - sv[1]*t01, u01 = sv[1]*t00 + cv[1]*t01;
                float u10 = cv[1]*t10 - sv[1]*t11, u11 = sv[1]*t10 + cv[1]*t11;  // RY(v1) w1
                float tmp = u01; u01 = u11; u11 = tmp;                            // CNOT(1->0)
                float p00 = cv[2]*u00 - sv[2]*u10, p01 = cv[2]*u01 - sv[2]*u11;
                float p10 = sv[2]*u00 + cv[2]*u10, p11 = sv[2]*u01 + cv[2]*u11;  // RY(v2) w0
                float q00 = cv[3]*p00 - sv[3]*p01, q01 = sv[3]*p00 + cv[3]*p01;
                float q10 = cv[3]*p10 - sv[3]*p11, q11 = sv[3]*p10 + cv[3]*p11;  // RY(v3) w1

                float z0 = q00*q00 + q01*q01 - q10*q10 - q11*q11;
                float z1 = q00*q00 + q10*q10 - q01*q01 - q11*q11;
                float x0 = 2.f * (q00*q10 + q01*q11);
                float x1 = 2.f * (q00*q01 + q10*q11);
                qf[t] = make_float4(z0, z1, x0, x1);
            }
        }
    }

    lds_fence();  // scls visible across lanes of this wave

    // ---- fused matvec: W chunks read straight from global (L2-hot, coalesced) ----
    if (active) {
        const float4* lw4 = (const float4*)lin_w;
        float ps[10];
        #pragma unroll
        for (int o = 0; o < 10; ++o) ps[o] = 0.f;

        #pragma unroll
        for (int t = 0; t < 4; ++t) {
            int p  = lane + t * 64;
            int pc = (p < 196) ? p : 195;        // clamp keeps loads in-bounds
            float m = (p < 196) ? 1.f : 0.f;
            float4 cl = *(const float4*)&scls[wave][4 * pc];
            float4 f = make_float4((cl.x + qf[t].x) * m, (cl.y + qf[t].y) * m,
                                   (cl.z + qf[t].z) * m, (cl.w + qf[t].w) * m);
            #pragma unroll
            for (int o = 0; o < 10; ++o) {
                float4 wv = lw4[o * 196 + pc];
                ps[o] += f.x * wv.x + f.y * wv.y + f.z * wv.z + f.w * wv.w;
            }
        }

        float lg[10];
        #pragma unroll
        for (int o = 0; o < 10; ++o) lg[o] = wave64_sum(ps[o]) + lin_b[o];

        // log_softmax over 10 (wave-uniform values)
        float mx = lg[0];
        #pragma unroll
        for (int o = 1; o < 10; ++o) mx = fmaxf(mx, lg[o]);
        float se = 0.f;
        #pragma unroll
        for (int o = 0; o < 10; ++o) se += __expf(lg[o] - mx);
        float ls = __logf(se);

        if (lane < 10) {
            float v = lg[0];
            #pragma unroll
            for (int o = 1; o < 10; ++o) v = (lane == o) ? lg[o] : v;
            out[(size_t)sample * 10 + lane] = v - mx - ls;
        }
    }
}

extern "C" void kernel_launch(void* const* d_in, const int* in_sizes, int n_in,
                              void* d_out, int out_size, void* d_ws, size_t ws_size,
                              hipStream_t stream) {
    const float* x          = (const float*)d_in[0];
    const float* conv_w     = (const float*)d_in[1];
    const float* bn_gamma   = (const float*)d_in[2];
    const float* bn_beta    = (const float*)d_in[3];
    const float* bn_mean    = (const float*)d_in[4];
    const float* bn_var     = (const float*)d_in[5];
    const float* var_params = (const float*)d_in[6];
    const float* lin_w      = (const float*)d_in[7];
    const float* lin_b      = (const float*)d_in[8];
    float* out = (float*)d_out;

    const int B = in_sizes[0] / 784;
    const int blocks = (B + NW - 1) / NW;
    quanv_fused<<<blocks, 256, 0, stream>>>(x, conv_w, bn_gamma, bn_beta, bn_mean,
                                            bn_var, var_params, lin_w, lin_b, out, B);
}

// Round 4
// 110.678 us; speedup vs baseline: 1.2645x; 1.0806x over previous
//
#include <hip/hip_runtime.h>
#include <math.h>

// QuanvolutionPlus fused kernel, round 4 (round-3 design, compile fix).
// vs round 2 (41us steady, VALU-issue bound ~1950 VALU instr/wave):
//  - 2 samples per wave (half-wave each): patch tail waste 23% -> 12.5%,
//    one 5-stage DPP reduce covers both samples (50 ops vs 120).
//  - matvec in f16: lin_w staged to LDS as f16 once per block, scls stored f16,
//    v_dot2_f32_f16 (2 MACs/instr) + packed f16 add for the fused add. Frees L1.
//  - no simg: conv reads 6 aligned float2 per patch straight from global (L1-hot,
//    image is 3KB/sample), halo handled by offset clamp + multiplicative mask.
//  - exactly one __syncthreads (lin_w staging); scls is per-half-wave (written
//    and read by the same wave) so the barrier also safely orders it.
// Compile fix vs round 3: half typedefs use __fp16 (the element type
// __builtin_amdgcn_cvt_pkrtz returns); scalar converts use (__fp16).
//
// Index facts (verified in rounds 1-2):
//   cls flat n = c*196 + p ; q flat n = 4p + k ; fused chunk p = n in [4p,4p+3]
//   logits[o] = sum_n fused[n] * lin_w[o*784+n] + lin_b[o]

#define NW 4                 // waves per block; 2 samples per wave -> 8 samples/block
#define SCLS_STRIDE 794      // f16 elems per sample; odd word count de-phases halves

typedef __fp16 h2 __attribute__((ext_vector_type(2)));
typedef __fp16 h4 __attribute__((ext_vector_type(4)));

#if __has_builtin(__builtin_amdgcn_fdot2)
#define FDOT2(a, b, c) __builtin_amdgcn_fdot2((a), (b), (c), false)
#else
__device__ __forceinline__ float FDOT2(h2 a, h2 b, float c) {
    return (float)a.x * (float)b.x + (float)a.y * (float)b.y + c;
}
#endif

// 32-lane segmented sum (both halves at once); returns {sum lanes0-31, sum lanes32-63}
__device__ __forceinline__ float2 red32x2(float x) {
    int v;
    v = __builtin_amdgcn_update_dpp(0, __float_as_int(x), 0x111, 0xf, 0xf, true); x += __int_as_float(v);
    v = __builtin_amdgcn_update_dpp(0, __float_as_int(x), 0x112, 0xf, 0xf, true); x += __int_as_float(v);
    v = __builtin_amdgcn_update_dpp(0, __float_as_int(x), 0x114, 0xf, 0xf, true); x += __int_as_float(v);
    v = __builtin_amdgcn_update_dpp(0, __float_as_int(x), 0x118, 0xf, 0xf, true); x += __int_as_float(v);
    v = __builtin_amdgcn_update_dpp(0, __float_as_int(x), 0x142, 0xa, 0xf, true); x += __int_as_float(v);
    float2 r;
    r.x = __int_as_float(__builtin_amdgcn_readlane(__float_as_int(x), 31));
    r.y = __int_as_float(__builtin_amdgcn_readlane(__float_as_int(x), 63));
    return r;
}

__global__ __launch_bounds__(256, 4)
void quanv_fused(const float* __restrict__ x,
                 const float* __restrict__ conv_w,
                 const float* __restrict__ bn_gamma,
                 const float* __restrict__ bn_beta,
                 const float* __restrict__ bn_mean,
                 const float* __restrict__ bn_var,
                 const float* __restrict__ var_params,
                 const float* __restrict__ lin_w,
                 const float* __restrict__ lin_b,
                 float* __restrict__ out, int B)
{
    __shared__ __align__(16) __fp16 lwh[7840];                     // 15680 B
    __shared__ __align__(16) __fp16 sclsAll[NW * 2 * SCLS_STRIDE]; // 12704 B

    const int tid  = threadIdx.x;
    const int wave = tid >> 6;
    const int lane = tid & 63;
    const int half = lane >> 5;
    const int l32  = lane & 31;

    const int s  = blockIdx.x * (NW * 2) + wave * 2 + half;
    const int sc = (s < B) ? s : (B - 1);
    const float* xs = x + (size_t)sc * 784;
    __fp16* myscls = &sclsAll[(wave * 2 + half) * SCLS_STRIDE];

    // ---- stage lin_w -> LDS as f16 (whole block, once) ----
    {
        const float4* src = (const float4*)lin_w;
        #pragma unroll
        for (int t = 0; t < 8; ++t) {
            int i = tid + t * 256;
            if (i < 1960) {
                float4 v = src[i];
                h2 a = __builtin_amdgcn_cvt_pkrtz(v.x, v.y);
                h2 b = __builtin_amdgcn_cvt_pkrtz(v.z, v.w);
                h4 w4 = { a.x, a.y, b.x, b.y };
                *(h4*)&lwh[4 * i] = w4;
            }
        }
    }

    // ---- uniform small params ----
    float w[36];
    #pragma unroll
    for (int k = 0; k < 36; ++k) w[k] = conv_w[k];
    float inv[4], addc[4];
    #pragma unroll
    for (int c = 0; c < 4; ++c) {
        float iv = bn_gamma[c] * rsqrtf(bn_var[c] + 1e-5f);
        inv[c]  = iv;
        addc[c] = bn_beta[c] - bn_mean[c] * iv;
    }
    float cv[4], sv[4];
    #pragma unroll
    for (int k = 0; k < 4; ++k) __sincosf(var_params[k] * 0.5f, &sv[k], &cv[k]);

    // ---- per-patch conv(4ch)+BN+ReLU -> scls(f16) ; quantum -> qh registers ----
    h2 qh[7][2];
    #pragma unroll
    for (int t = 0; t < 7; ++t) {
        int p = l32 + 32 * t;
        bool act = (p < 196);
        int pc = act ? p : 195;
        unsigned i = (unsigned)pc / 14u;
        int j = pc - (int)i * 14;
        int omid = (int)(2 * i) * 28 + 2 * j;      // row 2i, col 2j (element offset)

        // 6 aligned float2 loads; clamp keeps addresses in [0,783]
        float2 Rm = *(const float2*)(xs + omid);                       // a11 a12
        float2 Rb = *(const float2*)(xs + omid + 28);                  // a21 a22
        int ot = omid - 28; ot = (ot > 0) ? ot : 0;
        float2 Rt = *(const float2*)(xs + ot);                         // a01 a02 (row 2i-1)
        int olt = omid - 30; olt = (olt > 0) ? olt : 0;
        float2 Lt = *(const float2*)(xs + olt);                        // .y = a00
        int olm = omid - 2; olm = (olm > 0) ? olm : 0;
        float2 Lm = *(const float2*)(xs + olm);                        // .y = a10
        float2 Lb = *(const float2*)(xs + olm + 28);                   // .y = a20

        float mt = (i > 0) ? 1.f : 0.f;      // top row exists
        float ml = (j > 0) ? 1.f : 0.f;      // left col exists
        float a00 = Lt.y * (mt * ml), a01 = Rt.x * mt, a02 = Rt.y * mt;
        float a10 = Lm.y * ml,        a11 = Rm.x,      a12 = Rm.y;
        float a20 = Lb.y * ml,        a21 = Rb.x,      a22 = Rb.y;

        if (act) {
            #pragma unroll
            for (int c = 0; c < 4; ++c) {
                float h = w[c*9+0]*a00 + w[c*9+1]*a01 + w[c*9+2]*a02
                        + w[c*9+3]*a10 + w[c*9+4]*a11 + w[c*9+5]*a12
                        + w[c*9+6]*a20 + w[c*9+7]*a21 + w[c*9+8]*a22;
                h = h * inv[c] + addc[c];
                myscls[c * 196 + pc] = (__fp16)fmaxf(h, 0.f);
            }
        }

        // quantum over patch pixels a11(=x[2i][2j]) a12 a21 a22
        float ha = 0.5f * (a11 + a21);
        float hb = 0.5f * (a12 + a22);
        float c0, s0, c1, s1;
        __sincosf(ha, &s0, &c0);
        __sincosf(hb, &s1, &c1);
        float m00 = c0*c1, m01 = c0*s1;
        float m10 = s0*s1, m11 = s0*c1;                                  // enc + CNOT(0->1)
        float t00 = cv[0]*m00 - sv[0]*m10, t01 = cv[0]*m01 - sv[0]*m11;
        float t10 = sv[0]*m00 + cv[0]*m10, t11 = sv[0]*m01 + cv[0]*m11;  // RY(v0) w0
        float u00 = cv[1]*t00 - sv[1]*t01, u01 = sv[1]*t00 + cv[1]*t01;
        float u10 = cv[1]*t10 - sv[1]*t11, u11 = sv[1]*t10 + cv[1]*t11;  // RY(v1) w1
        float tmp = u01; u01 = u11; u11 = tmp;                            // CNOT(1->0)
        float p00 = cv[2]*u00 - sv[2]*u10, p01 = cv[2]*u01 - sv[2]*u11;
        float p10 = sv[2]*u00 + cv[2]*u10, p11 = sv[2]*u01 + cv[2]*u11;  // RY(v2) w0
        float q00 = cv[3]*p00 - sv[3]*p01, q01 = sv[3]*p00 + cv[3]*p01;
        float q10 = cv[3]*p10 - sv[3]*p11, q11 = sv[3]*p10 + cv[3]*p11;  // RY(v3) w1

        float z0 = q00*q00 + q01*q01 - q10*q10 - q11*q11;
        float z1 = q00*q00 + q10*q10 - q01*q01 - q11*q11;
        float x0 = 2.f * (q00*q10 + q01*q11);
        float x1 = 2.f * (q00*q01 + q10*q11);
        qh[t][0] = __builtin_amdgcn_cvt_pkrtz(z0, z1);
        qh[t][1] = __builtin_amdgcn_cvt_pkrtz(x0, x1);
    }

    __syncthreads();   // lin_w staging visible to all; also orders scls (lgkmcnt 0)

    // ---- fused matvec in f16: ps[o] += dot(fused chunk, w chunk) ----
    float ps[10];
    #pragma unroll
    for (int o = 0; o < 10; ++o) ps[o] = 0.f;

    const h2 hz = { (__fp16)0.f, (__fp16)0.f };
    #pragma unroll
    for (int t = 0; t < 7; ++t) {
        int p = l32 + 32 * t;
        bool act = (p < 196);
        int pc = act ? p : 195;
        h2 c0 = *(const h2*)&myscls[4 * pc];
        h2 c1 = *(const h2*)&myscls[4 * pc + 2];
        h2 f0 = c0 + qh[t][0];
        h2 f1 = c1 + qh[t][1];
        f0 = act ? f0 : hz;
        f1 = act ? f1 : hz;
        const __fp16* wbase = &lwh[4 * pc];
        #pragma unroll
        for (int o = 0; o < 10; ++o) {
            h4 wv = *(const h4*)&wbase[o * 784];
            h2 wlo = __builtin_shufflevector(wv, wv, 0, 1);
            h2 whi = __builtin_shufflevector(wv, wv, 2, 3);
            ps[o] = FDOT2(f0, wlo, ps[o]);
            ps[o] = FDOT2(f1, whi, ps[o]);
        }
    }

    // ---- reduce both halves at once; softmax; store ----
    float lg[10];
    #pragma unroll
    for (int o = 0; o < 10; ++o) {
        float2 r = red32x2(ps[o]);
        lg[o] = (half ? r.y : r.x) + lin_b[o];
    }

    float mx = lg[0];
    #pragma unroll
    for (int o = 1; o < 10; ++o) mx = fmaxf(mx, lg[o]);
    float se = 0.f;
    #pragma unroll
    for (int o = 0; o < 10; ++o) se += __expf(lg[o] - mx);
    float ls = __logf(se);

    int o32 = l32;
    if (o32 < 10 && s < B) {
        float v = lg[0];
        #pragma unroll
        for (int o = 1; o < 10; ++o) v = (o32 == o) ? lg[o] : v;
        out[(size_t)s * 10 + o32] = v - mx - ls;
    }
}

extern "C" void kernel_launch(void* const* d_in, const int* in_sizes, int n_in,
                              void* d_out, int out_size, void* d_ws, size_t ws_size,
                              hipStream_t stream) {
    const float* x          = (const float*)d_in[0];
    const float* conv_w     = (const float*)d_in[1];
    const float* bn_gamma   = (const float*)d_in[2];
    const float* bn_beta    = (const float*)d_in[3];
    const float* bn_mean    = (const float*)d_in[4];
    const float* bn_var     = (const float*)d_in[5];
    const float* var_params = (const float*)d_in[6];
    const float* lin_w      = (const float*)d_in[7];
    const float* lin_b      = (const float*)d_in[8];
    float* out = (float*)d_out;

    const int B = in_sizes[0] / 784;
    const int blocks = (B + NW * 2 - 1) / (NW * 2);
    quanv_fused<<<blocks, 256, 0, stream>>>(x, conv_w, bn_gamma, bn_beta, bn_mean,
                                            bn_var, var_params, lin_w, lin_b, out, B);
}